// Round 2
// baseline (56649.280 us; speedup 1.0000x reference)
//
#include <hip/hip_runtime.h>
#include <hip/hip_bf16.h>
#include <math.h>

#define BATCH 256
#define T_IN 256
#define T_OUT 32
#define E_DIM 512
#define H_DIM 1024
#define Y_DIM 1024
#define G_DIM 3072  // 3*H

// ---------------------------------------------------------------------------
// Dual GEMM: for z in {0,1}: C[M,N] = A[M,K] @ W[N,K]^T + bias[N]
// A row gather (set 0 only): row index = gather[row*gstride]; A==nullptr -> 0
// Tiles: 64x64, BK=16, 256 threads, 4x4 microtile per thread. fp32.
// ---------------------------------------------------------------------------
__global__ __launch_bounds__(256) void gemm_dual(
    const float* __restrict__ A0, int lda0, const int* __restrict__ g0, int gs0,
    const float* __restrict__ W0, const float* __restrict__ b0,
    float* __restrict__ C0, int K0,
    const float* __restrict__ A1, int lda1,
    const float* __restrict__ W1, const float* __restrict__ b1,
    float* __restrict__ C1, int K1,
    int M, int N)
{
    const int z = blockIdx.z;
    const float* A = z ? A1 : A0;
    const int lda = z ? lda1 : lda0;
    const int* gat = z ? nullptr : g0;
    const int gstride = z ? 0 : gs0;
    const float* W = z ? W1 : W0;
    const float* bias = z ? b1 : b0;
    float* C = z ? C1 : C0;
    const int K = z ? K1 : K0;

    __shared__ float As[16][68];
    __shared__ float Bs[16][68];

    const int tid = threadIdx.x;
    const int bm = blockIdx.x * 64;
    const int bn = blockIdx.y * 64;

    const int lr = tid >> 2;         // 0..63 load row
    const int lk = (tid & 3) << 2;   // 0,4,8,12 load k offset

    float acc[4][4] = {};

    const float* arow = nullptr;
    if (A) {
        int grow = bm + lr;
        int ridx = gat ? gat[(size_t)grow * gstride] : grow;
        arow = A + (size_t)ridx * lda;
    }
    const float* wrow = W + (size_t)(bn + lr) * K;

    const int tm = (tid >> 4) << 2;
    const int tn = (tid & 15) << 2;

    for (int k0 = 0; k0 < K; k0 += 16) {
        float4 av = make_float4(0.f, 0.f, 0.f, 0.f);
        if (A) av = *(const float4*)(arow + k0 + lk);
        float4 wv = *(const float4*)(wrow + k0 + lk);
        As[lk + 0][lr] = av.x; As[lk + 1][lr] = av.y;
        As[lk + 2][lr] = av.z; As[lk + 3][lr] = av.w;
        Bs[lk + 0][lr] = wv.x; Bs[lk + 1][lr] = wv.y;
        Bs[lk + 2][lr] = wv.z; Bs[lk + 3][lr] = wv.w;
        __syncthreads();
        #pragma unroll
        for (int k = 0; k < 16; ++k) {
            float a0 = As[k][tm + 0], a1 = As[k][tm + 1];
            float a2 = As[k][tm + 2], a3 = As[k][tm + 3];
            float w0 = Bs[k][tn + 0], w1 = Bs[k][tn + 1];
            float w2 = Bs[k][tn + 2], w3 = Bs[k][tn + 3];
            acc[0][0] += a0 * w0; acc[0][1] += a0 * w1; acc[0][2] += a0 * w2; acc[0][3] += a0 * w3;
            acc[1][0] += a1 * w0; acc[1][1] += a1 * w1; acc[1][2] += a1 * w2; acc[1][3] += a1 * w3;
            acc[2][0] += a2 * w0; acc[2][1] += a2 * w1; acc[2][2] += a2 * w2; acc[2][3] += a2 * w3;
            acc[3][0] += a3 * w0; acc[3][1] += a3 * w1; acc[3][2] += a3 * w2; acc[3][3] += a3 * w3;
        }
        __syncthreads();
    }

    #pragma unroll
    for (int i = 0; i < 4; ++i) {
        float* crow = C + (size_t)(bm + tm + i) * N + bn;
        #pragma unroll
        for (int j = 0; j < 4; ++j)
            crow[tn + j] = acc[i][j] + bias[bn + tn + j];
    }
}

// ---------------------------------------------------------------------------
// Fused GRU cell elementwise: h' = (1-z)*n + z*h  (torch gate order r,z,n)
// Optional bf16 copy of the new hidden into enc_out.
// ---------------------------------------------------------------------------
__global__ __launch_bounds__(256) void gru_fuse(
    const float* __restrict__ gi, const float* __restrict__ gh,
    const float* __restrict__ h, float* __restrict__ hout,
    __hip_bfloat16* __restrict__ copy_out)
{
    int i = blockIdx.x * 256 + threadIdx.x;      // 0..B*H
    int b = i >> 10;
    int j = i & 1023;
    const float* gib = gi + (size_t)b * G_DIM;
    const float* ghb = gh + (size_t)b * G_DIM;
    float ir = gib[j], iz = gib[H_DIM + j], in_ = gib[2 * H_DIM + j];
    float hr = ghb[j], hz = ghb[H_DIM + j], hn = ghb[2 * H_DIM + j];
    float r = 1.f / (1.f + expf(-(ir + hr)));
    float zz = 1.f / (1.f + expf(-(iz + hz)));
    float n = tanhf(in_ + r * hn);
    float hv = h[i];
    float o = (1.f - zz) * n + zz * hv;
    hout[i] = o;
    if (copy_out) copy_out[i] = __float2bfloat16(o);
}

// ---------------------------------------------------------------------------
// scores[b][s] = dot(enc_out[s][b][:], h2[b][:])   one wave per (s,b)
// enc is bf16, h2 is f32.
// ---------------------------------------------------------------------------
__global__ __launch_bounds__(256) void attn_scores(
    const __hip_bfloat16* __restrict__ enc, const float* __restrict__ h2,
    float* __restrict__ scores)
{
    int wid = (blockIdx.x * 256 + threadIdx.x) >> 6;  // 0..T_IN*B
    int lane = threadIdx.x & 63;
    int s = wid >> 8;
    int b = wid & 255;
    const __hip_bfloat162* e2 =
        (const __hip_bfloat162*)(enc + ((size_t)s * BATCH + b) * H_DIM);
    const float* hb = h2 + (size_t)b * H_DIM;
    float sum = 0.f;
    #pragma unroll
    for (int p = lane; p < H_DIM / 2; p += 64) {
        float2 ef = __bfloat1622float2(e2[p]);
        sum += ef.x * hb[2 * p] + ef.y * hb[2 * p + 1];
    }
    for (int off = 32; off; off >>= 1) sum += __shfl_down(sum, off);
    if (!lane) scores[(size_t)b * T_IN + s] = sum;
}

// softmax over s (T_IN=256) for each b; in place
__global__ __launch_bounds__(256) void softmax_rows(float* __restrict__ scores)
{
    int b = blockIdx.x, t = threadIdx.x;
    float v = scores[(size_t)b * T_IN + t];
    int lane = t & 63, w = t >> 6;
    float m = v;
    for (int off = 32; off; off >>= 1) m = fmaxf(m, __shfl_down(m, off));
    __shared__ float r1[4];
    if (!lane) r1[w] = m;
    __syncthreads();
    m = fmaxf(fmaxf(r1[0], r1[1]), fmaxf(r1[2], r1[3]));
    float ex = expf(v - m);
    float s = ex;
    for (int off = 32; off; off >>= 1) s += __shfl_down(s, off);
    __shared__ float r2[4];
    if (!lane) r2[w] = s;
    __syncthreads();
    s = r2[0] + r2[1] + r2[2] + r2[3];
    scores[(size_t)b * T_IN + t] = ex / s;
}

// attn[b][h] = sum_s alpha[b][s] * enc_out[s][b][h]; one block per b
__global__ __launch_bounds__(256) void attn_apply(
    const __hip_bfloat16* __restrict__ enc, const float* __restrict__ alpha,
    float* __restrict__ attn)
{
    int b = blockIdx.x, t = threadIdx.x;
    float acc[4] = {0.f, 0.f, 0.f, 0.f};
    for (int s = 0; s < T_IN; ++s) {
        float a = alpha[(size_t)b * T_IN + s];
        const __hip_bfloat16* e = enc + ((size_t)s * BATCH + b) * H_DIM;
        #pragma unroll
        for (int i = 0; i < 4; ++i) acc[i] += a * __bfloat162float(e[t + i * 256]);
    }
    #pragma unroll
    for (int i = 0; i < 4; ++i) attn[(size_t)b * H_DIM + t + i * 256] = acc[i];
}

// cat[b] = [attn[b], h2[b]]
__global__ __launch_bounds__(256) void concat_kernel(
    const float* __restrict__ attn, const float* __restrict__ h2,
    float* __restrict__ cat)
{
    int i = blockIdx.x * 256 + threadIdx.x;  // 0..B*2H
    int b = i >> 11;
    int j = i & 2047;
    cat[i] = (j < H_DIM) ? attn[(size_t)b * H_DIM + j]
                         : h2[(size_t)b * H_DIM + j - H_DIM];
}

// loss += sum_j y[b][t][j] * (logZ_b - logits[b][j]); one block per b
__global__ __launch_bounds__(256) void loss_kernel(
    const float* __restrict__ logits, const float* __restrict__ yt,
    float* __restrict__ loss_acc)
{
    int b = blockIdx.x, t = threadIdx.x;
    const float* lrow = logits + (size_t)b * Y_DIM;
    float l[4];
    #pragma unroll
    for (int i = 0; i < 4; ++i) l[i] = lrow[t + i * 256];
    float m = fmaxf(fmaxf(l[0], l[1]), fmaxf(l[2], l[3]));
    int lane = t & 63, w = t >> 6;
    for (int off = 32; off; off >>= 1) m = fmaxf(m, __shfl_down(m, off));
    __shared__ float sm[4];
    if (!lane) sm[w] = m;
    __syncthreads();
    m = fmaxf(fmaxf(sm[0], sm[1]), fmaxf(sm[2], sm[3]));
    float es = 0.f;
    #pragma unroll
    for (int i = 0; i < 4; ++i) es += expf(l[i] - m);
    for (int off = 32; off; off >>= 1) es += __shfl_down(es, off);
    __shared__ float ss[4];
    if (!lane) ss[w] = es;
    __syncthreads();
    float sum = ss[0] + ss[1] + ss[2] + ss[3];
    float logZ = m + logf(sum);
    const float* yrow = yt + (size_t)b * (T_OUT * Y_DIM);
    float part = 0.f;
    #pragma unroll
    for (int i = 0; i < 4; ++i) part += yrow[t + i * 256] * (logZ - l[i]);
    for (int off = 32; off; off >>= 1) part += __shfl_down(part, off);
    __shared__ float sp[4];
    if (!lane) sp[w] = part;
    __syncthreads();
    if (t == 0) atomicAdd(loss_acc, sp[0] + sp[1] + sp[2] + sp[3]);
}

__global__ __launch_bounds__(256) void ysum_kernel(
    const float* __restrict__ y, float* __restrict__ ysum, int n)
{
    float s = 0.f;
    for (int i = blockIdx.x * 256 + threadIdx.x; i < n; i += gridDim.x * 256)
        s += y[i];
    int lane = threadIdx.x & 63, w = threadIdx.x >> 6;
    for (int off = 32; off; off >>= 1) s += __shfl_down(s, off);
    __shared__ float sw[4];
    if (!lane) sw[w] = s;
    __syncthreads();
    if (!threadIdx.x) atomicAdd(ysum, sw[0] + sw[1] + sw[2] + sw[3]);
}

__global__ __launch_bounds__(256) void init_kernel(
    float* __restrict__ h0, float* __restrict__ h1,
    float* __restrict__ loss, float* __restrict__ ysum)
{
    int i = blockIdx.x * 256 + threadIdx.x;
    if (i < BATCH * H_DIM) { h0[i] = 0.f; h1[i] = 0.f; }
    if (i == 0) { *loss = 0.f; *ysum = 0.f; }
}

__global__ void final_kernel(const float* __restrict__ loss,
                             const float* __restrict__ ysum,
                             float* __restrict__ out)
{
    if (threadIdx.x == 0) out[0] = loss[0] / ysum[0];
}

// ---------------------------------------------------------------------------
extern "C" void kernel_launch(void* const* d_in, const int* in_sizes, int n_in,
                              void* d_out, int out_size, void* d_ws, size_t ws_size,
                              hipStream_t stream)
{
    const int*   x        = (const int*)d_in[0];
    const float* y        = (const float*)d_in[1];
    const float* emb      = (const float*)d_in[2];
    const float* eWih0    = (const float*)d_in[3];
    const float* eWhh0    = (const float*)d_in[4];
    const float* ebih0    = (const float*)d_in[5];
    const float* ebhh0    = (const float*)d_in[6];
    const float* eWih1    = (const float*)d_in[7];
    const float* eWhh1    = (const float*)d_in[8];
    const float* ebih1    = (const float*)d_in[9];
    const float* ebhh1    = (const float*)d_in[10];
    const float* dWih0    = (const float*)d_in[11];
    const float* dWhh0    = (const float*)d_in[12];
    const float* dbih0    = (const float*)d_in[13];
    const float* dbhh0    = (const float*)d_in[14];
    const float* dWih1    = (const float*)d_in[15];
    const float* dWhh1    = (const float*)d_in[16];
    const float* dbih1    = (const float*)d_in[17];
    const float* dbhh1    = (const float*)d_in[18];
    const float* mapW     = (const float*)d_in[19];
    const float* mapb     = (const float*)d_in[20];
    float* out = (float*)d_out;

    // workspace layout (bf16 enc_out = 128 MiB; total ~151 MB)
    char* wsb = (char*)d_ws;
    __hip_bfloat16* enc_bf = (__hip_bfloat16*)wsb;             // T*B*H bf16
    float* gi0 = (float*)(wsb + (size_t)T_IN * BATCH * H_DIM * 2);
    float* gh0     = gi0 + (size_t)BATCH * G_DIM;
    float* gi1     = gh0 + (size_t)BATCH * G_DIM;
    float* gh1     = gi1 + (size_t)BATCH * G_DIM;
    float* h0      = gh1 + (size_t)BATCH * G_DIM;
    float* h1      = h0 + (size_t)BATCH * H_DIM;
    float* scores  = h1 + (size_t)BATCH * H_DIM;
    float* attn    = scores + (size_t)BATCH * T_IN;
    float* cat     = attn + (size_t)BATCH * H_DIM;
    float* logits  = cat + (size_t)BATCH * 2 * H_DIM;
    float* loss_acc = logits + (size_t)BATCH * Y_DIM;
    float* ysum     = loss_acc + 1;

    dim3 blk(256);

    init_kernel<<<dim3(1024), blk, 0, stream>>>(h0, h1, loss_acc, ysum);
    ysum_kernel<<<dim3(2048), blk, 0, stream>>>(y, ysum, BATCH * T_OUT * Y_DIM);

    dim3 gGate(BATCH / 64, G_DIM / 64, 2);   // 4 x 48 x 2

    // -------- encoder: 2 layers fused per timestep --------
    for (int t = 0; t < T_IN; ++t) {
        gemm_dual<<<gGate, blk, 0, stream>>>(
            emb, E_DIM, x + t, T_IN, eWih0, ebih0, gi0, E_DIM,
            h0, H_DIM, eWhh0, ebhh0, gh0, H_DIM, BATCH, G_DIM);
        gru_fuse<<<dim3(1024), blk, 0, stream>>>(gi0, gh0, h0, h0, nullptr);
        gemm_dual<<<gGate, blk, 0, stream>>>(
            h0, H_DIM, nullptr, 0, eWih1, ebih1, gi1, H_DIM,
            h1, H_DIM, eWhh1, ebhh1, gh1, H_DIM, BATCH, G_DIM);
        gru_fuse<<<dim3(1024), blk, 0, stream>>>(
            gi1, gh1, h1, h1, enc_bf + (size_t)t * BATCH * H_DIM);
    }

    // -------- decoder --------
    for (int t = 0; t < T_OUT; ++t) {
        const float* yin = (t == 0) ? nullptr : (y + (size_t)(t - 1) * Y_DIM);
        gemm_dual<<<gGate, blk, 0, stream>>>(
            yin, T_OUT * Y_DIM, nullptr, 0, dWih0, dbih0, gi0, Y_DIM,
            h0, H_DIM, dWhh0, dbhh0, gh0, H_DIM, BATCH, G_DIM);
        gru_fuse<<<dim3(1024), blk, 0, stream>>>(gi0, gh0, h0, h0, nullptr);
        gemm_dual<<<gGate, blk, 0, stream>>>(
            h0, H_DIM, nullptr, 0, dWih1, dbih1, gi1, H_DIM,
            h1, H_DIM, dWhh1, dbhh1, gh1, H_DIM, BATCH, G_DIM);
        gru_fuse<<<dim3(1024), blk, 0, stream>>>(gi1, gh1, h1, h1, nullptr);

        attn_scores<<<dim3(T_IN * BATCH / 4), blk, 0, stream>>>(enc_bf, h1, scores);
        softmax_rows<<<dim3(BATCH), blk, 0, stream>>>(scores);
        attn_apply<<<dim3(BATCH), blk, 0, stream>>>(enc_bf, scores, attn);
        concat_kernel<<<dim3(2048), blk, 0, stream>>>(attn, h1, cat);

        dim3 gMap(BATCH / 64, Y_DIM / 64, 1);
        gemm_dual<<<gMap, blk, 0, stream>>>(
            cat, 2 * H_DIM, nullptr, 0, mapW, mapb, logits, 2 * H_DIM,
            nullptr, 0, nullptr, nullptr, nullptr, 0, BATCH, Y_DIM);
        loss_kernel<<<dim3(BATCH), blk, 0, stream>>>(
            logits, y + (size_t)t * Y_DIM, loss_acc);
    }

    final_kernel<<<dim3(1), dim3(64), 0, stream>>>(loss_acc, ysum, out);
}

// Round 3
// 15230.238 us; speedup vs baseline: 3.7195x; 3.7195x over previous
//
#include <hip/hip_runtime.h>
#include <hip/hip_bf16.h>
#include <math.h>

#define BATCH 256
#define T_IN 256
#define T_OUT 32
#define E_DIM 512
#define H_DIM 1024
#define Y_DIM 1024
#define G_DIM 3072  // 3*H

typedef __attribute__((ext_vector_type(8))) __bf16 bf16x8;
typedef __attribute__((ext_vector_type(4))) float f32x4;
typedef __attribute__((ext_vector_type(4))) unsigned int u32x4;

__device__ __forceinline__ unsigned short f2bf_raw(float x) {
    unsigned int u = __builtin_bit_cast(unsigned int, x);
    u += 0x7FFFu + ((u >> 16) & 1u);
    return (unsigned short)(u >> 16);
}

// ---------------------------------------------------------------------------
// f32 -> bf16 elementwise convert (weights, once per call)
// ---------------------------------------------------------------------------
__global__ __launch_bounds__(256) void f32_to_bf16(
    const float* __restrict__ src, short* __restrict__ dst, int n4)
{
    for (int i = blockIdx.x * 256 + threadIdx.x; i < n4; i += gridDim.x * 256) {
        float4 f = *(const float4*)(src + 4 * (size_t)i);
        short4 o;
        o.x = (short)f2bf_raw(f.x);
        o.y = (short)f2bf_raw(f.y);
        o.z = (short)f2bf_raw(f.z);
        o.w = (short)f2bf_raw(f.w);
        *(short4*)(dst + 4 * (size_t)i) = o;
    }
}

// ---------------------------------------------------------------------------
// Dual MFMA GEMM: for z in {0,1}: C[256,N] = A[256,K] @ W[N,K]^T + bias[N]
// A is bf16 (Ab) or f32-with-convert (Af); optional row gather for set 0.
// Tile 64x64, BK=32, 256 threads = 4 waves, each wave 32x32 (2x2 frags of
// 16x16x32 MFMA, f32 acc). LDS rows padded to 80B (2-way bank alias = free).
// ---------------------------------------------------------------------------
__global__ __launch_bounds__(256) void gemm_bf(
    const short* __restrict__ Ab0, const float* __restrict__ Af0,
    const int* __restrict__ g0, int gs0, int lda0, int K0,
    const short* __restrict__ W0, const float* __restrict__ b0, float* __restrict__ C0,
    const short* __restrict__ Ab1, const float* __restrict__ Af1,
    int lda1, int K1,
    const short* __restrict__ W1, const float* __restrict__ b1, float* __restrict__ C1,
    int N)
{
    const int z = blockIdx.z;
    const short* Ab = z ? Ab1 : Ab0;
    const float* Af = z ? Af1 : Af0;
    const int* gat = z ? nullptr : g0;
    const int gs = z ? 1 : gs0;
    const int lda = z ? lda1 : lda0;
    const int K = z ? K1 : K0;
    const short* W = z ? W1 : W0;
    const float* bias = z ? b1 : b0;
    float* C = z ? C1 : C0;

    __shared__ __align__(16) short As[64 * 40];
    __shared__ __align__(16) short Ws[64 * 40];

    const int tid = threadIdx.x;
    const int bm = blockIdx.x * 64;
    const int bn = blockIdx.y * 64;

    // staging: 64 rows x 4 chunks of 8 bf16 (16B)
    const int srow = tid >> 2;
    const int sch = tid & 3;

    const short* abase = nullptr;
    const float* afbase = nullptr;
    if (Ab) {
        int ridx = gat ? gat[(size_t)(bm + srow) * gs] : (bm + srow);
        abase = Ab + (size_t)ridx * lda;
    } else if (Af) {
        int ridx = gat ? gat[(size_t)(bm + srow) * gs] : (bm + srow);
        afbase = Af + (size_t)ridx * lda;
    }
    const short* wbase = W + (size_t)(bn + srow) * K;

    short* asdst = &As[srow * 40 + sch * 8];
    short* wsdst = &Ws[srow * 40 + sch * 8];

    // compute: wave -> 32x32 quadrant
    const int w = tid >> 6;
    const int lane = tid & 63;
    const int wm = (w >> 1) * 32;
    const int wn = (w & 1) * 32;
    const int lrow = lane & 15;
    const int lko = (lane >> 4) * 8;   // k element offset within BK=32

    const short* ar0 = &As[(wm + lrow) * 40 + lko];
    const short* ar1 = &As[(wm + 16 + lrow) * 40 + lko];
    const short* br0 = &Ws[(wn + lrow) * 40 + lko];
    const short* br1 = &Ws[(wn + 16 + lrow) * 40 + lko];

    f32x4 acc00 = {0.f, 0.f, 0.f, 0.f};
    f32x4 acc01 = acc00, acc10 = acc00, acc11 = acc00;

    for (int k0 = 0; k0 < K; k0 += 32) {
        u32x4 av;
        if (abase) {
            av = *(const u32x4*)(abase + k0 + sch * 8);
        } else if (afbase) {
            const float* fp = afbase + k0 + sch * 8;
            float4 f0 = *(const float4*)(fp);
            float4 f1 = *(const float4*)(fp + 4);
            av.x = ((unsigned)f2bf_raw(f0.y) << 16) | f2bf_raw(f0.x);
            av.y = ((unsigned)f2bf_raw(f0.w) << 16) | f2bf_raw(f0.z);
            av.z = ((unsigned)f2bf_raw(f1.y) << 16) | f2bf_raw(f1.x);
            av.w = ((unsigned)f2bf_raw(f1.w) << 16) | f2bf_raw(f1.z);
        } else {
            av.x = av.y = av.z = av.w = 0u;
        }
        u32x4 wv = *(const u32x4*)(wbase + k0 + sch * 8);
        *(u32x4*)asdst = av;
        *(u32x4*)wsdst = wv;
        __syncthreads();

        bf16x8 a0 = __builtin_bit_cast(bf16x8, *(const u32x4*)ar0);
        bf16x8 a1 = __builtin_bit_cast(bf16x8, *(const u32x4*)ar1);
        bf16x8 b0v = __builtin_bit_cast(bf16x8, *(const u32x4*)br0);
        bf16x8 b1v = __builtin_bit_cast(bf16x8, *(const u32x4*)br1);

        acc00 = __builtin_amdgcn_mfma_f32_16x16x32_bf16(a0, b0v, acc00, 0, 0, 0);
        acc01 = __builtin_amdgcn_mfma_f32_16x16x32_bf16(a0, b1v, acc01, 0, 0, 0);
        acc10 = __builtin_amdgcn_mfma_f32_16x16x32_bf16(a1, b0v, acc10, 0, 0, 0);
        acc11 = __builtin_amdgcn_mfma_f32_16x16x32_bf16(a1, b1v, acc11, 0, 0, 0);

        __syncthreads();
    }

    // epilogue: D row=(lane>>4)*4+j, col=lane&15  [verified m89/m91 layout]
    const int rbase = (lane >> 4) * 4;
    const int cl = lane & 15;
    #pragma unroll
    for (int fm = 0; fm < 2; ++fm) {
        #pragma unroll
        for (int fn = 0; fn < 2; ++fn) {
            f32x4 a = fm ? (fn ? acc11 : acc10) : (fn ? acc01 : acc00);
            int col = bn + wn + fn * 16 + cl;
            float bv = bias[col];
            #pragma unroll
            for (int j = 0; j < 4; ++j) {
                int row = bm + wm + fm * 16 + rbase + j;
                C[(size_t)row * N + col] = a[j] + bv;
            }
        }
    }
}

// ---------------------------------------------------------------------------
// Fused GRU cell elementwise (torch gate order r,z,n).
// Writes f32 h, bf16 h shadow, optional bf16 copy into enc_out.
// ---------------------------------------------------------------------------
__global__ __launch_bounds__(256) void gru_fuse(
    const float* __restrict__ gi, const float* __restrict__ gh,
    const float* __restrict__ h, float* __restrict__ hout,
    short* __restrict__ hbf, short* __restrict__ copy_out)
{
    int i = blockIdx.x * 256 + threadIdx.x;      // 0..B*H
    int b = i >> 10;
    int j = i & 1023;
    const float* gib = gi + (size_t)b * G_DIM;
    const float* ghb = gh + (size_t)b * G_DIM;
    float ir = gib[j], iz = gib[H_DIM + j], in_ = gib[2 * H_DIM + j];
    float hr = ghb[j], hz = ghb[H_DIM + j], hn = ghb[2 * H_DIM + j];
    float r = 1.f / (1.f + expf(-(ir + hr)));
    float zz = 1.f / (1.f + expf(-(iz + hz)));
    float n = tanhf(in_ + r * hn);
    float hv = h[i];
    float o = (1.f - zz) * n + zz * hv;
    hout[i] = o;
    short ob = (short)f2bf_raw(o);
    hbf[i] = ob;
    if (copy_out) copy_out[i] = ob;
}

// ---------------------------------------------------------------------------
// scores[b][s] = dot(enc_bf[s][b][:], h2[b][:])   one wave per (s,b)
// ---------------------------------------------------------------------------
__global__ __launch_bounds__(256) void attn_scores(
    const short* __restrict__ enc, const float* __restrict__ h2,
    float* __restrict__ scores)
{
    int wid = (blockIdx.x * 256 + threadIdx.x) >> 6;  // 0..T_IN*B
    int lane = threadIdx.x & 63;
    int s = wid >> 8;
    int b = wid & 255;
    const unsigned int* e2 =
        (const unsigned int*)(enc + ((size_t)s * BATCH + b) * H_DIM);
    const float* hb = h2 + (size_t)b * H_DIM;
    float sum = 0.f;
    #pragma unroll
    for (int p = lane; p < H_DIM / 2; p += 64) {
        unsigned int u = e2[p];
        float lo = __builtin_bit_cast(float, u << 16);
        float hi = __builtin_bit_cast(float, u & 0xFFFF0000u);
        sum += lo * hb[2 * p] + hi * hb[2 * p + 1];
    }
    for (int off = 32; off; off >>= 1) sum += __shfl_down(sum, off);
    if (!lane) scores[(size_t)b * T_IN + s] = sum;
}

// softmax over s (T_IN=256) for each b; in place
__global__ __launch_bounds__(256) void softmax_rows(float* __restrict__ scores)
{
    int b = blockIdx.x, t = threadIdx.x;
    float v = scores[(size_t)b * T_IN + t];
    int lane = t & 63, w = t >> 6;
    float m = v;
    for (int off = 32; off; off >>= 1) m = fmaxf(m, __shfl_down(m, off));
    __shared__ float r1[4];
    if (!lane) r1[w] = m;
    __syncthreads();
    m = fmaxf(fmaxf(r1[0], r1[1]), fmaxf(r1[2], r1[3]));
    float ex = expf(v - m);
    float s = ex;
    for (int off = 32; off; off >>= 1) s += __shfl_down(s, off);
    __shared__ float r2[4];
    if (!lane) r2[w] = s;
    __syncthreads();
    s = r2[0] + r2[1] + r2[2] + r2[3];
    scores[(size_t)b * T_IN + t] = ex / s;
}

// attn[b][h] = sum_s alpha[b][s] * enc_bf[s][b][h]; one block per b
__global__ __launch_bounds__(256) void attn_apply(
    const short* __restrict__ enc, const float* __restrict__ alpha,
    float* __restrict__ attn)
{
    int b = blockIdx.x, t = threadIdx.x;
    float acc[4] = {0.f, 0.f, 0.f, 0.f};
    for (int s = 0; s < T_IN; ++s) {
        float a = alpha[(size_t)b * T_IN + s];
        const short* e = enc + ((size_t)s * BATCH + b) * H_DIM;
        #pragma unroll
        for (int i = 0; i < 4; ++i) {
            unsigned int u = ((unsigned int)(unsigned short)e[t + i * 256]) << 16;
            acc[i] += a * __builtin_bit_cast(float, u);
        }
    }
    #pragma unroll
    for (int i = 0; i < 4; ++i) attn[(size_t)b * H_DIM + t + i * 256] = acc[i];
}

// cat_bf[b] = bf16([attn[b], h2[b]])
__global__ __launch_bounds__(256) void concat_kernel(
    const float* __restrict__ attn, const float* __restrict__ h2,
    short* __restrict__ cat)
{
    int i = blockIdx.x * 256 + threadIdx.x;  // 0..B*2H
    int b = i >> 11;
    int j = i & 2047;
    float v = (j < H_DIM) ? attn[(size_t)b * H_DIM + j]
                          : h2[(size_t)b * H_DIM + j - H_DIM];
    cat[i] = (short)f2bf_raw(v);
}

// loss += sum_j y[b][t][j] * (logZ_b - logits[b][j]); one block per b
__global__ __launch_bounds__(256) void loss_kernel(
    const float* __restrict__ logits, const float* __restrict__ yt,
    float* __restrict__ loss_acc)
{
    int b = blockIdx.x, t = threadIdx.x;
    const float* lrow = logits + (size_t)b * Y_DIM;
    float l[4];
    #pragma unroll
    for (int i = 0; i < 4; ++i) l[i] = lrow[t + i * 256];
    float m = fmaxf(fmaxf(l[0], l[1]), fmaxf(l[2], l[3]));
    int lane = t & 63, w = t >> 6;
    for (int off = 32; off; off >>= 1) m = fmaxf(m, __shfl_down(m, off));
    __shared__ float sm[4];
    if (!lane) sm[w] = m;
    __syncthreads();
    m = fmaxf(fmaxf(sm[0], sm[1]), fmaxf(sm[2], sm[3]));
    float es = 0.f;
    #pragma unroll
    for (int i = 0; i < 4; ++i) es += expf(l[i] - m);
    for (int off = 32; off; off >>= 1) es += __shfl_down(es, off);
    __shared__ float ss[4];
    if (!lane) ss[w] = es;
    __syncthreads();
    float sum = ss[0] + ss[1] + ss[2] + ss[3];
    float logZ = m + logf(sum);
    const float* yrow = yt + (size_t)b * (T_OUT * Y_DIM);
    float part = 0.f;
    #pragma unroll
    for (int i = 0; i < 4; ++i) part += yrow[t + i * 256] * (logZ - l[i]);
    for (int off = 32; off; off >>= 1) part += __shfl_down(part, off);
    __shared__ float sp[4];
    if (!lane) sp[w] = part;
    __syncthreads();
    if (t == 0) atomicAdd(loss_acc, sp[0] + sp[1] + sp[2] + sp[3]);
}

__global__ __launch_bounds__(256) void ysum_kernel(
    const float* __restrict__ y, float* __restrict__ ysum, int n)
{
    float s = 0.f;
    for (int i = blockIdx.x * 256 + threadIdx.x; i < n; i += gridDim.x * 256)
        s += y[i];
    int lane = threadIdx.x & 63, w = threadIdx.x >> 6;
    for (int off = 32; off; off >>= 1) s += __shfl_down(s, off);
    __shared__ float sw[4];
    if (!lane) sw[w] = s;
    __syncthreads();
    if (!threadIdx.x) atomicAdd(ysum, sw[0] + sw[1] + sw[2] + sw[3]);
}

__global__ __launch_bounds__(256) void init_kernel(
    float* __restrict__ h0, float* __restrict__ h1,
    short* __restrict__ h0bf, short* __restrict__ h1bf,
    float* __restrict__ loss, float* __restrict__ ysum)
{
    int i = blockIdx.x * 256 + threadIdx.x;
    if (i < BATCH * H_DIM) {
        h0[i] = 0.f; h1[i] = 0.f; h0bf[i] = 0; h1bf[i] = 0;
    }
    if (i == 0) { *loss = 0.f; *ysum = 0.f; }
}

__global__ void final_kernel(const float* __restrict__ loss,
                             const float* __restrict__ ysum,
                             float* __restrict__ out)
{
    if (threadIdx.x == 0) out[0] = loss[0] / ysum[0];
}

// ---------------------------------------------------------------------------
extern "C" void kernel_launch(void* const* d_in, const int* in_sizes, int n_in,
                              void* d_out, int out_size, void* d_ws, size_t ws_size,
                              hipStream_t stream)
{
    const int*   x     = (const int*)d_in[0];
    const float* y     = (const float*)d_in[1];
    const float* emb   = (const float*)d_in[2];
    const float* eWih0 = (const float*)d_in[3];
    const float* eWhh0 = (const float*)d_in[4];
    const float* ebih0 = (const float*)d_in[5];
    const float* ebhh0 = (const float*)d_in[6];
    const float* eWih1 = (const float*)d_in[7];
    const float* eWhh1 = (const float*)d_in[8];
    const float* ebih1 = (const float*)d_in[9];
    const float* ebhh1 = (const float*)d_in[10];
    const float* dWih0 = (const float*)d_in[11];
    const float* dWhh0 = (const float*)d_in[12];
    const float* dbih0 = (const float*)d_in[13];
    const float* dbhh0 = (const float*)d_in[14];
    const float* dWih1 = (const float*)d_in[15];
    const float* dWhh1 = (const float*)d_in[16];
    const float* dbih1 = (const float*)d_in[17];
    const float* dbhh1 = (const float*)d_in[18];
    const float* mapW  = (const float*)d_in[19];
    const float* mapb  = (const float*)d_in[20];
    float* out = (float*)d_out;

    // ---- workspace layout (~195 MiB) ----
    char* p = (char*)d_ws;
    short* enc_bf = (short*)p;               p += (size_t)T_IN * BATCH * H_DIM * 2;
    short* eWih0b = (short*)p;               p += (size_t)G_DIM * E_DIM * 2;
    short* eWhh0b = (short*)p;               p += (size_t)G_DIM * H_DIM * 2;
    short* eWih1b = (short*)p;               p += (size_t)G_DIM * H_DIM * 2;
    short* eWhh1b = (short*)p;               p += (size_t)G_DIM * H_DIM * 2;
    short* dWih0b = (short*)p;               p += (size_t)G_DIM * Y_DIM * 2;
    short* dWhh0b = (short*)p;               p += (size_t)G_DIM * H_DIM * 2;
    short* dWih1b = (short*)p;               p += (size_t)G_DIM * H_DIM * 2;
    short* dWhh1b = (short*)p;               p += (size_t)G_DIM * H_DIM * 2;
    short* mapWb  = (short*)p;               p += (size_t)Y_DIM * 2 * H_DIM * 2;
    float* gi0 = (float*)p;                  p += (size_t)BATCH * G_DIM * 4;
    float* gh0 = (float*)p;                  p += (size_t)BATCH * G_DIM * 4;
    float* gi1 = (float*)p;                  p += (size_t)BATCH * G_DIM * 4;
    float* gh1 = (float*)p;                  p += (size_t)BATCH * G_DIM * 4;
    float* h0  = (float*)p;                  p += (size_t)BATCH * H_DIM * 4;
    float* h1  = (float*)p;                  p += (size_t)BATCH * H_DIM * 4;
    short* h0bf = (short*)p;                 p += (size_t)BATCH * H_DIM * 2;
    short* h1bf = (short*)p;                 p += (size_t)BATCH * H_DIM * 2;
    float* scores = (float*)p;               p += (size_t)BATCH * T_IN * 4;
    float* attn   = (float*)p;               p += (size_t)BATCH * H_DIM * 4;
    short* cat_bf = (short*)p;               p += (size_t)BATCH * 2 * H_DIM * 2;
    float* logits = (float*)p;               p += (size_t)BATCH * Y_DIM * 4;
    float* loss_acc = (float*)p;             p += 8;
    float* ysum = loss_acc + 1;

    dim3 blk(256);

    // ---- weight conversion (once per call; deterministic) ----
    f32_to_bf16<<<dim3(512), blk, 0, stream>>>(eWih0, eWih0b, G_DIM * E_DIM / 4);
    f32_to_bf16<<<dim3(512), blk, 0, stream>>>(eWhh0, eWhh0b, G_DIM * H_DIM / 4);
    f32_to_bf16<<<dim3(512), blk, 0, stream>>>(eWih1, eWih1b, G_DIM * H_DIM / 4);
    f32_to_bf16<<<dim3(512), blk, 0, stream>>>(eWhh1, eWhh1b, G_DIM * H_DIM / 4);
    f32_to_bf16<<<dim3(512), blk, 0, stream>>>(dWih0, dWih0b, G_DIM * Y_DIM / 4);
    f32_to_bf16<<<dim3(512), blk, 0, stream>>>(dWhh0, dWhh0b, G_DIM * H_DIM / 4);
    f32_to_bf16<<<dim3(512), blk, 0, stream>>>(dWih1, dWih1b, G_DIM * H_DIM / 4);
    f32_to_bf16<<<dim3(512), blk, 0, stream>>>(dWhh1, dWhh1b, G_DIM * H_DIM / 4);
    f32_to_bf16<<<dim3(512), blk, 0, stream>>>(mapW, mapWb, Y_DIM * 2 * H_DIM / 4);

    init_kernel<<<dim3(1024), blk, 0, stream>>>(h0, h1, h0bf, h1bf, loss_acc, ysum);
    ysum_kernel<<<dim3(2048), blk, 0, stream>>>(y, ysum, BATCH * T_OUT * Y_DIM);

    dim3 gGate(BATCH / 64, G_DIM / 64, 2);   // 4 x 48 x 2

    // -------- encoder: 2 layers fused per timestep --------
    for (int t = 0; t < T_IN; ++t) {
        // z0: gi0 = emb[x[:,t]] @ eWih0^T (f32 gather-convert, K=512)
        // z1: gh0 = h0 @ eWhh0^T (bf16, K=1024)
        gemm_bf<<<gGate, blk, 0, stream>>>(
            nullptr, emb, x + t, T_IN, E_DIM, E_DIM, eWih0b, ebih0, gi0,
            h0bf, nullptr, H_DIM, H_DIM, eWhh0b, ebhh0, gh0, G_DIM);
        gru_fuse<<<dim3(1024), blk, 0, stream>>>(gi0, gh0, h0, h0, h0bf, nullptr);
        // z0: gi1 = h0 @ eWih1^T ; z1: gh1 = h1 @ eWhh1^T
        gemm_bf<<<gGate, blk, 0, stream>>>(
            h0bf, nullptr, nullptr, 1, H_DIM, H_DIM, eWih1b, ebih1, gi1,
            h1bf, nullptr, H_DIM, H_DIM, eWhh1b, ebhh1, gh1, G_DIM);
        gru_fuse<<<dim3(1024), blk, 0, stream>>>(
            gi1, gh1, h1, h1, h1bf, enc_bf + (size_t)t * BATCH * H_DIM);
    }

    // -------- decoder --------
    for (int t = 0; t < T_OUT; ++t) {
        const float* yin = (t == 0) ? nullptr : (y + (size_t)(t - 1) * Y_DIM);
        gemm_bf<<<gGate, blk, 0, stream>>>(
            nullptr, yin, nullptr, 1, T_OUT * Y_DIM, Y_DIM, dWih0b, dbih0, gi0,
            h0bf, nullptr, H_DIM, H_DIM, dWhh0b, dbhh0, gh0, G_DIM);
        gru_fuse<<<dim3(1024), blk, 0, stream>>>(gi0, gh0, h0, h0, h0bf, nullptr);
        gemm_bf<<<gGate, blk, 0, stream>>>(
            h0bf, nullptr, nullptr, 1, H_DIM, H_DIM, dWih1b, dbih1, gi1,
            h1bf, nullptr, H_DIM, H_DIM, dWhh1b, dbhh1, gh1, G_DIM);
        gru_fuse<<<dim3(1024), blk, 0, stream>>>(gi1, gh1, h1, h1, h1bf, nullptr);

        attn_scores<<<dim3(T_IN * BATCH / 4), blk, 0, stream>>>(enc_bf, h1, scores);
        softmax_rows<<<dim3(BATCH), blk, 0, stream>>>(scores);
        attn_apply<<<dim3(BATCH), blk, 0, stream>>>(enc_bf, scores, attn);
        concat_kernel<<<dim3(2048), blk, 0, stream>>>(attn, h1, cat_bf);

        dim3 gMap(BATCH / 64, Y_DIM / 64, 1);
        gemm_bf<<<gMap, blk, 0, stream>>>(
            cat_bf, nullptr, nullptr, 1, 2 * H_DIM, 2 * H_DIM, mapWb, mapb, logits,
            nullptr, nullptr, 0, 0, nullptr, nullptr, nullptr, Y_DIM);
        loss_kernel<<<dim3(BATCH), blk, 0, stream>>>(
            logits, y + (size_t)t * Y_DIM, loss_acc);
    }

    final_kernel<<<dim3(1), dim3(64), 0, stream>>>(loss_acc, ysum, out);
}